// Round 14
// baseline (452.563 us; speedup 1.0000x reference)
//
#include <hip/hip_runtime.h>
#include <math.h>

typedef __bf16 bf16x8 __attribute__((ext_vector_type(8)));
typedef __bf16 bf16x4 __attribute__((ext_vector_type(4)));
typedef float f32x4 __attribute__((ext_vector_type(4)));
typedef float f32x2 __attribute__((ext_vector_type(2)));
typedef unsigned int u32x2 __attribute__((ext_vector_type(2)));
typedef unsigned int u32x4 __attribute__((ext_vector_type(4)));

#define LOG2E 1.4426950408889634f

static __device__ __forceinline__ float lrelu(float e) { return e > 0.0f ? e : 0.2f * e; }
static __device__ __forceinline__ float fexp2(float x) { return __builtin_amdgcn_exp2f(x); }

static __device__ __forceinline__ void dec16(u32x4 u, float* f) {
#pragma unroll
  for (int i = 0; i < 4; i++) {
    f32x2 a = __builtin_amdgcn_cvt_pk_f32_fp8(u[i], false);
    f32x2 b = __builtin_amdgcn_cvt_pk_f32_fp8(u[i], true);
    f[i * 4 + 0] = a.x;
    f[i * 4 + 1] = a.y;
    f[i * 4 + 2] = b.x;
    f[i * 4 + 3] = b.y;
  }
}

static __device__ __forceinline__ void dec8(unsigned int lo, unsigned int hi, float* f) {
  f32x2 a = __builtin_amdgcn_cvt_pk_f32_fp8(lo, false);
  f32x2 b = __builtin_amdgcn_cvt_pk_f32_fp8(lo, true);
  f32x2 c = __builtin_amdgcn_cvt_pk_f32_fp8(hi, false);
  f32x2 d = __builtin_amdgcn_cvt_pk_f32_fp8(hi, true);
  f[0] = a.x; f[1] = a.y; f[2] = b.x; f[3] = b.y;
  f[4] = c.x; f[5] = c.y; f[6] = d.x; f[7] = d.y;
}

// permuted-position -> true-channel map: p = blk*64 + l16*4 + ng  <->  c = blk*64 + ng*16 + l16
static __device__ __forceinline__ int cmap(int p) {
  return (p & ~63) + (p & 3) * 16 + ((p & 63) >> 2);
}

// ---------------- prep: x->bf16, weight transposes, zero cnt + sync counters ----------------
__global__ void prep_kernel(const float* __restrict__ x, __bf16* __restrict__ xb, int n4,
                            const float* __restrict__ W0, __bf16* __restrict__ Bt0,
                            const float* __restrict__ W1, __bf16* __restrict__ Bt1,
                            const float* __restrict__ W2, __bf16* __restrict__ Bt2, int FIN,
                            int* __restrict__ cnt, int* __restrict__ syncc, int n) {
  int cb = (n4 + 255) / 256;
  int b = blockIdx.x;
  if (b < cb) {
    int i = b * 256 + threadIdx.x;
    if (i < n4) {
      f32x4 v = ((const f32x4*)x)[i];
      bf16x4 o = {(__bf16)v.x, (__bf16)v.y, (__bf16)v.z, (__bf16)v.w};
      ((bf16x4*)xb)[i] = o;
    }
    return;
  }
  b -= cb;
  if (b < 256) {  // Bt0[256][FIN] = W0^T (x unpermuted)
    for (int k = threadIdx.x; k < FIN; k += 256) Bt0[b * FIN + k] = (__bf16)W0[k * 256 + b];
    return;
  }
  b -= 256;
  if (b < 256) {  // Bt1[n][p] = W1[cmap(p)][n]
    int k = threadIdx.x;
    Bt1[b * 256 + k] = (__bf16)W1[cmap(k) * 256 + b];
    return;
  }
  b -= 256;
  if (b < 64) {  // Bt2[n][p] = W2[cmap(p)][n]
    int k = threadIdx.x;
    Bt2[b * 256 + k] = (__bf16)W2[cmap(k) * 64 + b];
    return;
  }
  b -= 64;
  // zero cnt[] and the 2 soft-barrier counters (re-init every launch for graph replay)
  int i = b * 256 + threadIdx.x;
  if (i < n) cnt[i] = 0;
  if (b == 0 && threadIdx.x < 2) syncc[threadIdx.x] = 0;
}

// ---------------- FUSED: layer-0 GEMM + CSR count (independent halves overlap) ----------------
template <int K, int NT>
__global__ __launch_bounds__(256) void count_gemm_kernel(
    const __bf16* __restrict__ A, const __bf16* __restrict__ Bt,
    const float* __restrict__ a_src, const float* __restrict__ a_dst,
    unsigned char* __restrict__ C, float* __restrict__ es, float* __restrict__ ed, int M,
    int gmx, const int* __restrict__ dst, int* __restrict__ cnt, int* __restrict__ rank, int E,
    int n) {
  constexpr int Nc = NT * 64;
  constexpr int H = NT;
  __shared__ __bf16 Bs[NT * 64][40];
  if ((int)blockIdx.x >= gmx) {
    int base = (blockIdx.x - gmx) * 1024 + threadIdx.x;
    int d4[4];
    bool ok[4];
#pragma unroll
    for (int t = 0; t < 4; t++) {
      int e = base + t * 256;
      ok[t] = (e < E + n);
      d4[t] = ok[t] ? ((e < E) ? dst[e] : (e - E)) : 0;
    }
#pragma unroll
    for (int t = 0; t < 4; t++)
      if (ok[t]) rank[base + t * 256] = atomicAdd(&cnt[d4[t]], 1);
    return;
  }
  int bid = blockIdx.x;
  int tid = threadIdx.x;
  int wave = tid >> 6;
  int lane = tid & 63;
  int quad = lane >> 4;
  int l16 = lane & 15;
  int rowBase = bid * 64 + wave * 16;
  f32x4 acc[NT * 4] = {};
  int arow = rowBase + l16;
  arow = (arow < M) ? arow : (M - 1);
  const __bf16* Aptr = &A[(size_t)arow * K + quad * 8];
  int sr = tid >> 2;
  int sc = (tid & 3) * 8;
  for (int kb = 0; kb < K; kb += 32) {
#pragma unroll
    for (int it = 0; it < NT; it++) {
      int r = it * 64 + sr;
      *(bf16x8*)&Bs[r][sc] = *(const bf16x8*)&Bt[(size_t)r * K + kb + sc];
    }
    __syncthreads();
    bf16x8 a = *(const bf16x8*)&Aptr[kb];
#pragma unroll
    for (int ng = 0; ng < NT * 4; ng++) {
      bf16x8 b = *(const bf16x8*)&Bs[ng * 16 + l16][quad * 8];
      acc[ng] = __builtin_amdgcn_mfma_f32_16x16x32_bf16(a, b, acc[ng], 0, 0, 0);
    }
    __syncthreads();
  }
  float asv[NT * 4], adv[NT * 4];
#pragma unroll
  for (int ng = 0; ng < NT * 4; ng++) {
    int c = (ng >> 2) * 64 + (ng & 3) * 16 + l16;
    asv[ng] = a_src[c];
    adv[ng] = a_dst[c];
  }
#pragma unroll
  for (int r = 0; r < 4; r++) {
    int row = rowBase + quad * 4 + r;
#pragma unroll
    for (int h = 0; h < H; h++) {
      float ss = 0.f, sd = 0.f;
#pragma unroll
      for (int g = 0; g < 4; g++) {
        float hv = acc[h * 4 + g][r];
        ss += hv * asv[h * 4 + g];
        sd += hv * adv[h * 4 + g];
      }
#pragma unroll
      for (int o = 1; o < 16; o <<= 1) {
        ss += __shfl_xor(ss, o);
        sd += __shfl_xor(sd, o);
      }
      if (row < M) {
        if (l16 == 0) {
          es[row * H + h] = ss * LOG2E;  // pre-scaled for exp2 in aggregate
          ed[row * H + h] = sd * LOG2E;
        }
        unsigned int pk = 0;
        pk = __builtin_amdgcn_cvt_pk_fp8_f32(acc[h * 4 + 0][r], acc[h * 4 + 1][r], pk, false);
        pk = __builtin_amdgcn_cvt_pk_fp8_f32(acc[h * 4 + 2][r], acc[h * 4 + 3][r], pk, true);
        *(unsigned int*)&C[(size_t)row * Nc + h * 64 + l16 * 4] = pk;
      }
    }
  }
}

// -------- FUSED scan+scatter: one dispatch, 256 co-resident blocks, 2 soft barriers --------
// blocks [0,nb): block-local LDS scan of cnt -> offsets (local) + partials; barrier 1;
// every scan block wave-scans partials (<=64) and adds its base; barrier 2;
// ALL 256 blocks grid-stride the atomic-free scatter. Grid=256 <= CU count => co-resident.
__global__ __launch_bounds__(1024) void scan_scatter_kernel(
    const int* __restrict__ counts, int* __restrict__ offsets, int* __restrict__ partials,
    int* __restrict__ syncc, int n, int nb, const int* __restrict__ srcE,
    const int* __restrict__ dstE, const int* __restrict__ rank, int* __restrict__ out_sorted,
    int E) {
  __shared__ int sh[1024];
  __shared__ int sbase;
  int tid = threadIdx.x;
  int b = blockIdx.x;
  int EE = E + n;
  if (b < nb) {
    int i = b * 1024 + tid;
    int v = (i < n) ? counts[i] : 0;
    sh[tid] = v;
    __syncthreads();
    for (int d = 1; d < 1024; d <<= 1) {
      int t = (tid >= d) ? sh[tid - d] : 0;
      __syncthreads();
      sh[tid] += t;
      __syncthreads();
    }
    if (i < n) offsets[i] = sh[tid] - v;  // block-local exclusive
    if (tid == 1023) partials[b] = sh[1023];
    __threadfence();
    __syncthreads();
    if (tid == 0) {
      atomicAdd(&syncc[0], 1);
      while (__hip_atomic_load(&syncc[0], __ATOMIC_ACQUIRE, __HIP_MEMORY_SCOPE_AGENT) < nb)
        __builtin_amdgcn_s_sleep(1);
    }
    __syncthreads();
    // redundant wave-scan of partials in wave 0; base for this block via lane b
    if (tid < 64) {
      int lane = tid;
      int pv = (lane < nb) ? partials[lane] : 0;
      int orig = pv;
      for (int d = 1; d < 64; d <<= 1) {
        int t = __shfl_up(pv, d);
        if (lane >= d) pv += t;
      }
      if (lane == b) sbase = pv - orig;
      if (b == 0 && lane == nb - 1) offsets[n] = pv;  // grand total
    }
    __syncthreads();
    int base = sbase;
    int i2 = b * 1024 + tid;
    if (i2 < n) offsets[i2] += base;
    __threadfence();
    __syncthreads();
    if (tid == 0) atomicAdd(&syncc[1], 1);
  }
  // barrier 2: wait for all offsets final
  if (tid == 0) {
    while (__hip_atomic_load(&syncc[1], __ATOMIC_ACQUIRE, __HIP_MEMORY_SCOPE_AGENT) < nb)
      __builtin_amdgcn_s_sleep(1);
  }
  __syncthreads();
  // grid-stride atomic-free scatter
  for (int e = b * 1024 + tid; e < EE; e += 256 * 1024) {
    int s = (e < E) ? srcE[e] : (e - E);
    int d = (e < E) ? dstE[e] : (e - E);
    out_sorted[offsets[d] + rank[e]] = s;
  }
}

// plain single-pass GEMM (layers 1/2)
template <int K, int NT>
__global__ __launch_bounds__(256) void gemm2_kernel(const __bf16* __restrict__ A,
                                                    const __bf16* __restrict__ Bt,
                                                    const float* __restrict__ a_src,
                                                    const float* __restrict__ a_dst,
                                                    unsigned char* __restrict__ C,
                                                    float* __restrict__ es,
                                                    float* __restrict__ ed, int M) {
  constexpr int Nc = NT * 64;
  constexpr int H = NT;
  __shared__ __bf16 Bs[NT * 64][40];
  int tid = threadIdx.x;
  int wave = tid >> 6;
  int lane = tid & 63;
  int quad = lane >> 4;
  int l16 = lane & 15;
  int rowBase = blockIdx.x * 64 + wave * 16;
  f32x4 acc[NT * 4] = {};
  int arow = rowBase + l16;
  arow = (arow < M) ? arow : (M - 1);
  const __bf16* Aptr = &A[(size_t)arow * K + quad * 8];
  int sr = tid >> 2;
  int sc = (tid & 3) * 8;
  for (int kb = 0; kb < K; kb += 32) {
#pragma unroll
    for (int it = 0; it < NT; it++) {
      int r = it * 64 + sr;
      *(bf16x8*)&Bs[r][sc] = *(const bf16x8*)&Bt[(size_t)r * K + kb + sc];
    }
    __syncthreads();
    bf16x8 a = *(const bf16x8*)&Aptr[kb];
#pragma unroll
    for (int ng = 0; ng < NT * 4; ng++) {
      bf16x8 b = *(const bf16x8*)&Bs[ng * 16 + l16][quad * 8];
      acc[ng] = __builtin_amdgcn_mfma_f32_16x16x32_bf16(a, b, acc[ng], 0, 0, 0);
    }
    __syncthreads();
  }
  float asv[NT * 4], adv[NT * 4];
#pragma unroll
  for (int ng = 0; ng < NT * 4; ng++) {
    int c = (ng >> 2) * 64 + (ng & 3) * 16 + l16;
    asv[ng] = a_src[c];
    adv[ng] = a_dst[c];
  }
#pragma unroll
  for (int r = 0; r < 4; r++) {
    int row = rowBase + quad * 4 + r;
#pragma unroll
    for (int h = 0; h < H; h++) {
      float ss = 0.f, sd = 0.f;
#pragma unroll
      for (int g = 0; g < 4; g++) {
        float hv = acc[h * 4 + g][r];
        ss += hv * asv[h * 4 + g];
        sd += hv * adv[h * 4 + g];
      }
#pragma unroll
      for (int o = 1; o < 16; o <<= 1) {
        ss += __shfl_xor(ss, o);
        sd += __shfl_xor(sd, o);
      }
      if (row < M) {
        if (l16 == 0) {
          es[row * H + h] = ss * LOG2E;
          ed[row * H + h] = sd * LOG2E;
        }
        unsigned int pk = 0;
        pk = __builtin_amdgcn_cvt_pk_fp8_f32(acc[h * 4 + 0][r], acc[h * 4 + 1][r], pk, false);
        pk = __builtin_amdgcn_cvt_pk_fp8_f32(acc[h * 4 + 2][r], acc[h * 4 + 3][r], pk, true);
        *(unsigned int*)&C[(size_t)row * Nc + h * 64 + l16 * 4] = pk;
      }
    }
  }
}

// ------- aggregation, HC=256: fp8 gather, 4 edges/wave via quads, index-prefetch pipeline -------
__global__ void agg256_kernel(const unsigned char* __restrict__ h, const int* __restrict__ offsets,
                              const int* __restrict__ src_sorted, const float* __restrict__ es,
                              const float* __restrict__ ed, const float* __restrict__ bias,
                              __bf16* __restrict__ out, int n) {
  int node = blockIdx.x * (blockDim.x >> 6) + (threadIdx.x >> 6);
  int lane = threadIdx.x & 63;
  if (node >= n) return;
  int quad = lane >> 4;
  int l16 = lane & 15;  // positions l16*16 .. +16
  int hd = l16 >> 2;
  float myEd = ed[node * 4 + hd];
  int off = offsets[node];
  int deg = offsets[node + 1] - off;
  float acc[16] = {};
  float sw = 0.f;
  int j = 0;
  int s0a = 0, s1a = 0;
  if (j + 8 <= deg) {
    s0a = src_sorted[off + j + quad];
    s1a = src_sorted[off + j + 4 + quad];
  }
  for (; j + 8 <= deg;) {
    int jn = j + 8;
    int s0 = s0a, s1 = s1a;
    if (jn + 8 <= deg) {  // prefetch next iteration's indices
      s0a = src_sorted[off + jn + quad];
      s1a = src_sorted[off + jn + 4 + quad];
    }
    float e0 = es[s0 * 4 + hd];
    float e1 = es[s1 * 4 + hd];
    u32x4 u0 = *(const u32x4*)&h[(size_t)s0 * 256 + l16 * 16];
    u32x4 u1 = *(const u32x4*)&h[(size_t)s1 * 256 + l16 * 16];
    float w0 = fexp2(lrelu(e0 + myEd));
    float w1 = fexp2(lrelu(e1 + myEd));
    sw += w0 + w1;
    float f[16];
    dec16(u0, f);
#pragma unroll
    for (int k = 0; k < 16; k++) acc[k] += w0 * f[k];
    dec16(u1, f);
#pragma unroll
    for (int k = 0; k < 16; k++) acc[k] += w1 * f[k];
    j = jn;
  }
  for (; j < deg; j += 4) {  // tail: 1 edge per quad
    if (quad < deg - j) {
      int s = src_sorted[off + j + quad];
      float w = fexp2(lrelu(es[s * 4 + hd] + myEd));
      sw += w;
      u32x4 u = *(const u32x4*)&h[(size_t)s * 256 + l16 * 16];
      float f[16];
      dec16(u, f);
#pragma unroll
      for (int k = 0; k < 16; k++) acc[k] += w * f[k];
    }
  }
  sw += __shfl_xor(sw, 16);
  sw += __shfl_xor(sw, 32);
#pragma unroll
  for (int k = 0; k < 16; k++) {
    acc[k] += __shfl_xor(acc[k], 16);
    acc[k] += __shfl_xor(acc[k], 32);
  }
  float invS = 1.0f / (sw + 1e-16f);
  if (quad == 0) {
    bf16x8 o0, o1;
#pragma unroll
    for (int k = 0; k < 16; k++) {
      int c = hd * 64 + (k & 3) * 16 + (l16 & 3) * 4 + (k >> 2);  // cmap(l16*16+k)
      float v = fmaxf(acc[k] * invS + bias[c], 0.f);
      if (k < 8) o0[k] = (__bf16)v; else o1[k - 8] = (__bf16)v;
    }
    *(bf16x8*)&out[(size_t)node * 256 + l16 * 16] = o0;
    *(bf16x8*)&out[(size_t)node * 256 + l16 * 16 + 8] = o1;
  }
}

// ------- aggregation, HC=64 + FUSED final linear: p[i] = (agg_i + b2) . lin_w (fp8 gather) ------
__global__ void agg64_kernel(const unsigned char* __restrict__ h, const int* __restrict__ offsets,
                             const int* __restrict__ src_sorted, const float* __restrict__ es,
                             const float* __restrict__ ed, const float* __restrict__ bias,
                             const float* __restrict__ lin_w, float* __restrict__ pnode, int n) {
  int node = blockIdx.x * (blockDim.x >> 6) + (threadIdx.x >> 6);
  int lane = threadIdx.x & 63;
  if (node >= n) return;
  int grp = lane >> 3;
  int l8 = lane & 7;
  float myEd = ed[node];
  int off = offsets[node];
  int deg = offsets[node + 1] - off;
  float acc[8] = {};
  float sw = 0.f;
  int j = 0;
  for (; j + 8 <= deg; j += 8) {
    int s = src_sorted[off + j + grp];
    float w = fexp2(lrelu(es[s] + myEd));
    sw += w;
    u32x2 u = *(const u32x2*)&h[(size_t)s * 64 + l8 * 8];
    float f[8];
    dec8(u.x, u.y, f);
#pragma unroll
    for (int k = 0; k < 8; k++) acc[k] += w * f[k];
  }
  if (j < deg && grp < deg - j) {
    int s = src_sorted[off + j + grp];
    float w = fexp2(lrelu(es[s] + myEd));
    sw += w;
    u32x2 u = *(const u32x2*)&h[(size_t)s * 64 + l8 * 8];
    float f[8];
    dec8(u.x, u.y, f);
#pragma unroll
    for (int k = 0; k < 8; k++) acc[k] += w * f[k];
  }
#pragma unroll
  for (int o = 8; o < 64; o <<= 1) {
    sw += __shfl_xor(sw, o);
#pragma unroll
    for (int k = 0; k < 8; k++) acc[k] += __shfl_xor(acc[k], o);
  }
  float invS = 1.0f / (sw + 1e-16f);
  float p = 0.f;
#pragma unroll
  for (int k = 0; k < 8; k++) {
    int c = (k & 3) * 16 + l8 * 2 + (k >> 2);  // cmap(l8*8+k)
    p += (acc[k] * invS + bias[c]) * lin_w[c];
  }
#pragma unroll
  for (int o = 1; o < 8; o <<= 1) p += __shfl_xor(p, o);
  if (lane == 0) pnode[node] = p;
}

// ---------------- FUSED pool+final: block g binary-searches its segment, reduces, writes out ----
static __device__ __forceinline__ int lowerb(const int* __restrict__ a, int n, int key) {
  int lo = 0, hi = n;
  while (lo < hi) {
    int mid = (lo + hi) >> 1;
    if (a[mid] < key) lo = mid + 1; else hi = mid;
  }
  return lo;
}

__global__ void poolfinal_kernel(const float* __restrict__ pnode, const int* __restrict__ batch,
                                 const float* __restrict__ lin_b, float* __restrict__ out, int n) {
  __shared__ float ws[4];
  int g = blockIdx.x;
  int start = lowerb(batch, n, g);
  int end = lowerb(batch, n, g + 1);
  float acc = 0.f;
  for (int i = start + threadIdx.x; i < end; i += 256) acc += pnode[i];
  for (int o = 32; o > 0; o >>= 1) acc += __shfl_down(acc, o);
  if ((threadIdx.x & 63) == 0) ws[threadIdx.x >> 6] = acc;
  __syncthreads();
  if (threadIdx.x == 0) {
    float total = ws[0] + ws[1] + ws[2] + ws[3];
    out[g] = total / fmaxf((float)(end - start), 1.0f) + lin_b[0];
  }
}

extern "C" void kernel_launch(void* const* d_in, const int* in_sizes, int n_in, void* d_out,
                              int out_size, void* d_ws, size_t ws_size, hipStream_t stream) {
  const float* x = (const float*)d_in[0];
  const int* edge_index = (const int*)d_in[1];
  const int* batch = (const int*)d_in[2];
  const float* W0 = (const float*)d_in[3];
  const float* a_src0 = (const float*)d_in[4];
  const float* a_dst0 = (const float*)d_in[5];
  const float* b0 = (const float*)d_in[6];
  const float* W1 = (const float*)d_in[7];
  const float* a_src1 = (const float*)d_in[8];
  const float* a_dst1 = (const float*)d_in[9];
  const float* b1 = (const float*)d_in[10];
  const float* W2 = (const float*)d_in[11];
  const float* a_src2 = (const float*)d_in[12];
  const float* a_dst2 = (const float*)d_in[13];
  const float* b2 = (const float*)d_in[14];
  const float* lin_w = (const float*)d_in[15];
  const float* lin_b = (const float*)d_in[16];
  float* out = (float*)d_out;

  const int N = in_sizes[2];      // 50000
  const int E = in_sizes[1] / 2;  // 800000
  const int EE = E + N;
  const int G = 64;
  const int FIN = in_sizes[0] / N;  // 128

  const int* srcArr = edge_index;
  const int* dstArr = edge_index + E;

  // workspace carve (256B aligned)
  size_t off = 0;
  auto alloc = [&](size_t bytes) -> void* {
    off = (off + 255) & ~(size_t)255;
    void* p = (char*)d_ws + off;
    off += bytes;
    return p;
  };
  __bf16* xb = (__bf16*)alloc((size_t)N * FIN * 2);
  unsigned char* hA = (unsigned char*)alloc((size_t)N * 256);  // GEMM out, fp8 permuted
  __bf16* hB = (__bf16*)alloc((size_t)N * 256 * 2);            // aggregate out, bf16 permuted
  unsigned char* h2 = (unsigned char*)alloc((size_t)N * 64);   // layer2 GEMM out, fp8 permuted
  float* pnode = (float*)alloc((size_t)N * 4);
  __bf16* Bt0 = (__bf16*)alloc((size_t)256 * FIN * 2);
  __bf16* Bt1 = (__bf16*)alloc((size_t)256 * 256 * 2);
  __bf16* Bt2 = (__bf16*)alloc((size_t)64 * 256 * 2);
  float* es = (float*)alloc((size_t)N * 4 * 4);
  float* ed = (float*)alloc((size_t)N * 4 * 4);
  int* offsets = (int*)alloc((size_t)(N + 1) * 4);
  int* partials = (int*)alloc((size_t)64 * 4);
  int* rank = (int*)alloc((size_t)EE * 4);
  int* src_sorted = (int*)alloc((size_t)EE * 4);
  int* cnt = (int*)alloc((size_t)N * 4);
  int* syncc = (int*)alloc((size_t)2 * 4);
  (void)ws_size;

  int n4 = N * FIN / 4;
  int cb = (n4 + 255) / 256;
  int nz = (N + 255) / 256;
  int ebc4 = (EE + 1023) / 1024;  // 4 edges per thread (count)
  int nb = (N + 1023) / 1024;     // scan blocks
  int nwb = (N + 3) / 4;          // aggregate: one node per wave, 4 waves/block
  int gmx = (N + 63) / 64;        // GEMM M-blocks (64 rows each)

  // ---- prep (x->bf16, weight transposes, zero cnt+sync) ----
  prep_kernel<<<cb + 576 + nz, 256, 0, stream>>>(x, xb, n4, W0, Bt0, W1, Bt1, W2, Bt2, FIN, cnt,
                                                 syncc, N);

  // ---- layer-0 GEMM + CSR count (fused; count's atomic cadence hides behind MFMA) ----
  count_gemm_kernel<128, 4><<<gmx + ebc4, 256, 0, stream>>>(
      xb, Bt0, a_src0, a_dst0, hA, es, ed, N, gmx, dstArr, cnt, rank, E, N);

  // ---- CSR scan + scatter: ONE dispatch with 2 soft barriers (256 co-resident blocks) ----
  scan_scatter_kernel<<<256, 1024, 0, stream>>>(cnt, offsets, partials, syncc, N, nb, srcArr,
                                                dstArr, rank, src_sorted, E);

  // ---- layer 0 aggregate ----
  agg256_kernel<<<nwb, 256, 0, stream>>>(hA, offsets, src_sorted, es, ed, b0, hB, N);

  // ---- layer 1: 256 -> 4x64 concat, relu ----
  gemm2_kernel<256, 4><<<gmx, 256, 0, stream>>>(hB, Bt1, a_src1, a_dst1, hA, es, ed, N);
  agg256_kernel<<<nwb, 256, 0, stream>>>(hA, offsets, src_sorted, es, ed, b1, hB, N);

  // ---- layer 2: 256 -> 1x64, single head; final linear fused into aggregate ----
  gemm2_kernel<256, 1><<<gmx, 256, 0, stream>>>(hB, Bt2, a_src2, a_dst2, h2, es, ed, N);
  agg64_kernel<<<nwb, 256, 0, stream>>>(h2, offsets, src_sorted, es, ed, b2, lin_w, pnode, N);

  // ---- fused global mean pool + bias (binary-search segments) ----
  poolfinal_kernel<<<G, 256, 0, stream>>>(pnode, batch, lin_b, out, N);
}

// Round 15
// 321.616 us; speedup vs baseline: 1.4072x; 1.4072x over previous
//
#include <hip/hip_runtime.h>
#include <math.h>

typedef __bf16 bf16x8 __attribute__((ext_vector_type(8)));
typedef __bf16 bf16x4 __attribute__((ext_vector_type(4)));
typedef float f32x4 __attribute__((ext_vector_type(4)));
typedef float f32x2 __attribute__((ext_vector_type(2)));
typedef unsigned int u32x2 __attribute__((ext_vector_type(2)));
typedef unsigned int u32x4 __attribute__((ext_vector_type(4)));

#define LOG2E 1.4426950408889634f

static __device__ __forceinline__ float lrelu(float e) { return e > 0.0f ? e : 0.2f * e; }
static __device__ __forceinline__ float fexp2(float x) { return __builtin_amdgcn_exp2f(x); }

static __device__ __forceinline__ void dec16(u32x4 u, float* f) {
#pragma unroll
  for (int i = 0; i < 4; i++) {
    f32x2 a = __builtin_amdgcn_cvt_pk_f32_fp8(u[i], false);
    f32x2 b = __builtin_amdgcn_cvt_pk_f32_fp8(u[i], true);
    f[i * 4 + 0] = a.x;
    f[i * 4 + 1] = a.y;
    f[i * 4 + 2] = b.x;
    f[i * 4 + 3] = b.y;
  }
}

static __device__ __forceinline__ void dec8(unsigned int lo, unsigned int hi, float* f) {
  f32x2 a = __builtin_amdgcn_cvt_pk_f32_fp8(lo, false);
  f32x2 b = __builtin_amdgcn_cvt_pk_f32_fp8(lo, true);
  f32x2 c = __builtin_amdgcn_cvt_pk_f32_fp8(hi, false);
  f32x2 d = __builtin_amdgcn_cvt_pk_f32_fp8(hi, true);
  f[0] = a.x; f[1] = a.y; f[2] = b.x; f[3] = b.y;
  f[4] = c.x; f[5] = c.y; f[6] = d.x; f[7] = d.y;
}

// permuted-position -> true-channel map: p = blk*64 + l16*4 + ng  <->  c = blk*64 + ng*16 + l16
static __device__ __forceinline__ int cmap(int p) {
  return (p & ~63) + (p & 3) * 16 + ((p & 63) >> 2);
}

// ---------------- prep: x->bf16, weight transposes, zero cnt ----------------
__global__ void prep_kernel(const float* __restrict__ x, __bf16* __restrict__ xb, int n4,
                            const float* __restrict__ W0, __bf16* __restrict__ Bt0,
                            const float* __restrict__ W1, __bf16* __restrict__ Bt1,
                            const float* __restrict__ W2, __bf16* __restrict__ Bt2, int FIN,
                            int* __restrict__ cnt, int n) {
  int cb = (n4 + 255) / 256;
  int b = blockIdx.x;
  if (b < cb) {
    int i = b * 256 + threadIdx.x;
    if (i < n4) {
      f32x4 v = ((const f32x4*)x)[i];
      bf16x4 o = {(__bf16)v.x, (__bf16)v.y, (__bf16)v.z, (__bf16)v.w};
      ((bf16x4*)xb)[i] = o;
    }
    return;
  }
  b -= cb;
  if (b < 256) {  // Bt0[256][FIN] = W0^T (x unpermuted)
    for (int k = threadIdx.x; k < FIN; k += 256) Bt0[b * FIN + k] = (__bf16)W0[k * 256 + b];
    return;
  }
  b -= 256;
  if (b < 256) {  // Bt1[n][p] = W1[cmap(p)][n]
    int k = threadIdx.x;
    Bt1[b * 256 + k] = (__bf16)W1[cmap(k) * 256 + b];
    return;
  }
  b -= 256;
  if (b < 64) {  // Bt2[n][p] = W2[cmap(p)][n]
    int k = threadIdx.x;
    Bt2[b * 256 + k] = (__bf16)W2[cmap(k) * 64 + b];
    return;
  }
  b -= 64;
  // zero cnt[] (re-init every launch: harness re-poisons d_ws)
  int i = b * 256 + threadIdx.x;
  if (i < n) cnt[i] = 0;
}

// ---------------- FUSED: layer-0 GEMM + CSR count (independent halves overlap) ----------------
template <int K, int NT>
__global__ __launch_bounds__(256) void count_gemm_kernel(
    const __bf16* __restrict__ A, const __bf16* __restrict__ Bt,
    const float* __restrict__ a_src, const float* __restrict__ a_dst,
    unsigned char* __restrict__ C, float* __restrict__ es, float* __restrict__ ed, int M,
    int gmx, const int* __restrict__ dst, int* __restrict__ cnt, int* __restrict__ rank, int E,
    int n) {
  constexpr int Nc = NT * 64;
  constexpr int H = NT;
  __shared__ __bf16 Bs[NT * 64][40];
  if ((int)blockIdx.x >= gmx) {
    int base = (blockIdx.x - gmx) * 1024 + threadIdx.x;
    int d4[4];
    bool ok[4];
#pragma unroll
    for (int t = 0; t < 4; t++) {
      int e = base + t * 256;
      ok[t] = (e < E + n);
      d4[t] = ok[t] ? ((e < E) ? dst[e] : (e - E)) : 0;
    }
#pragma unroll
    for (int t = 0; t < 4; t++)
      if (ok[t]) rank[base + t * 256] = atomicAdd(&cnt[d4[t]], 1);
    return;
  }
  int bid = blockIdx.x;
  int tid = threadIdx.x;
  int wave = tid >> 6;
  int lane = tid & 63;
  int quad = lane >> 4;
  int l16 = lane & 15;
  int rowBase = bid * 64 + wave * 16;
  f32x4 acc[NT * 4] = {};
  int arow = rowBase + l16;
  arow = (arow < M) ? arow : (M - 1);
  const __bf16* Aptr = &A[(size_t)arow * K + quad * 8];
  int sr = tid >> 2;
  int sc = (tid & 3) * 8;
  for (int kb = 0; kb < K; kb += 32) {
#pragma unroll
    for (int it = 0; it < NT; it++) {
      int r = it * 64 + sr;
      *(bf16x8*)&Bs[r][sc] = *(const bf16x8*)&Bt[(size_t)r * K + kb + sc];
    }
    __syncthreads();
    bf16x8 a = *(const bf16x8*)&Aptr[kb];
#pragma unroll
    for (int ng = 0; ng < NT * 4; ng++) {
      bf16x8 b = *(const bf16x8*)&Bs[ng * 16 + l16][quad * 8];
      acc[ng] = __builtin_amdgcn_mfma_f32_16x16x32_bf16(a, b, acc[ng], 0, 0, 0);
    }
    __syncthreads();
  }
  float asv[NT * 4], adv[NT * 4];
#pragma unroll
  for (int ng = 0; ng < NT * 4; ng++) {
    int c = (ng >> 2) * 64 + (ng & 3) * 16 + l16;
    asv[ng] = a_src[c];
    adv[ng] = a_dst[c];
  }
#pragma unroll
  for (int r = 0; r < 4; r++) {
    int row = rowBase + quad * 4 + r;
#pragma unroll
    for (int h = 0; h < H; h++) {
      float ss = 0.f, sd = 0.f;
#pragma unroll
      for (int g = 0; g < 4; g++) {
        float hv = acc[h * 4 + g][r];
        ss += hv * asv[h * 4 + g];
        sd += hv * adv[h * 4 + g];
      }
#pragma unroll
      for (int o = 1; o < 16; o <<= 1) {
        ss += __shfl_xor(ss, o);
        sd += __shfl_xor(sd, o);
      }
      if (row < M) {
        if (l16 == 0) {
          es[row * H + h] = ss * LOG2E;  // pre-scaled for exp2 in aggregate
          ed[row * H + h] = sd * LOG2E;
        }
        unsigned int pk = 0;
        pk = __builtin_amdgcn_cvt_pk_fp8_f32(acc[h * 4 + 0][r], acc[h * 4 + 1][r], pk, false);
        pk = __builtin_amdgcn_cvt_pk_fp8_f32(acc[h * 4 + 2][r], acc[h * 4 + 3][r], pk, true);
        *(unsigned int*)&C[(size_t)row * Nc + h * 64 + l16 * 4] = pk;
      }
    }
  }
}

// phase 1: per-block exclusive scan of 1024 elements + block totals
__global__ __launch_bounds__(1024) void scan1_kernel(const int* __restrict__ counts,
                                                     int* __restrict__ offsets,
                                                     int* __restrict__ partials, int n) {
  __shared__ int sh[1024];
  int tid = threadIdx.x;
  int i = blockIdx.x * 1024 + tid;
  int v = (i < n) ? counts[i] : 0;
  sh[tid] = v;
  __syncthreads();
  for (int d = 1; d < 1024; d <<= 1) {
    int t = (tid >= d) ? sh[tid - d] : 0;
    __syncthreads();
    sh[tid] += t;
    __syncthreads();
  }
  if (i < n) offsets[i] = sh[tid] - v;  // block-local exclusive
  if (tid == 1023) partials[blockIdx.x] = sh[1023];
}

// phase 2+3 fused: every block's wave redundantly scans partials (nb<=64), adds its block's base
__global__ __launch_bounds__(1024) void scan3_kernel(int* __restrict__ offsets,
                                                     const int* __restrict__ partials, int n,
                                                     int nb) {
  int lane = threadIdx.x & 63;
  int v = (lane < nb) ? partials[lane] : 0;
  int orig = v;
  for (int d = 1; d < 64; d <<= 1) {
    int t = __shfl_up(v, d);
    if (lane >= d) v += t;
  }
  int w = v - orig;  // exclusive prefix
  int base = __shfl(w, blockIdx.x);
  int total = __shfl(v, 63);
  int i = blockIdx.x * 1024 + threadIdx.x;
  if (i < n) offsets[i] += base;
  if (blockIdx.x == 0 && threadIdx.x == 0) offsets[n] = total;
}

// atomic-free scatter: 4 edges/thread, out_sorted[offsets[d]+rank[e]] = s
__global__ void scatter_kernel(const int* __restrict__ srcE, const int* __restrict__ dstE,
                               const int* __restrict__ offsets, const int* __restrict__ rank,
                               int* __restrict__ out_sorted, int E, int n) {
  int base = blockIdx.x * 1024 + threadIdx.x;
#pragma unroll
  for (int t = 0; t < 4; t++) {
    int e = base + t * 256;
    if (e < E + n) {
      int s = (e < E) ? srcE[e] : (e - E);
      int d = (e < E) ? dstE[e] : (e - E);
      out_sorted[offsets[d] + rank[e]] = s;
    }
  }
}

// plain single-pass GEMM (layers 1/2)
template <int K, int NT>
__global__ __launch_bounds__(256) void gemm2_kernel(const __bf16* __restrict__ A,
                                                    const __bf16* __restrict__ Bt,
                                                    const float* __restrict__ a_src,
                                                    const float* __restrict__ a_dst,
                                                    unsigned char* __restrict__ C,
                                                    float* __restrict__ es,
                                                    float* __restrict__ ed, int M) {
  constexpr int Nc = NT * 64;
  constexpr int H = NT;
  __shared__ __bf16 Bs[NT * 64][40];
  int tid = threadIdx.x;
  int wave = tid >> 6;
  int lane = tid & 63;
  int quad = lane >> 4;
  int l16 = lane & 15;
  int rowBase = blockIdx.x * 64 + wave * 16;
  f32x4 acc[NT * 4] = {};
  int arow = rowBase + l16;
  arow = (arow < M) ? arow : (M - 1);
  const __bf16* Aptr = &A[(size_t)arow * K + quad * 8];
  int sr = tid >> 2;
  int sc = (tid & 3) * 8;
  for (int kb = 0; kb < K; kb += 32) {
#pragma unroll
    for (int it = 0; it < NT; it++) {
      int r = it * 64 + sr;
      *(bf16x8*)&Bs[r][sc] = *(const bf16x8*)&Bt[(size_t)r * K + kb + sc];
    }
    __syncthreads();
    bf16x8 a = *(const bf16x8*)&Aptr[kb];
#pragma unroll
    for (int ng = 0; ng < NT * 4; ng++) {
      bf16x8 b = *(const bf16x8*)&Bs[ng * 16 + l16][quad * 8];
      acc[ng] = __builtin_amdgcn_mfma_f32_16x16x32_bf16(a, b, acc[ng], 0, 0, 0);
    }
    __syncthreads();
  }
  float asv[NT * 4], adv[NT * 4];
#pragma unroll
  for (int ng = 0; ng < NT * 4; ng++) {
    int c = (ng >> 2) * 64 + (ng & 3) * 16 + l16;
    asv[ng] = a_src[c];
    adv[ng] = a_dst[c];
  }
#pragma unroll
  for (int r = 0; r < 4; r++) {
    int row = rowBase + quad * 4 + r;
#pragma unroll
    for (int h = 0; h < H; h++) {
      float ss = 0.f, sd = 0.f;
#pragma unroll
      for (int g = 0; g < 4; g++) {
        float hv = acc[h * 4 + g][r];
        ss += hv * asv[h * 4 + g];
        sd += hv * adv[h * 4 + g];
      }
#pragma unroll
      for (int o = 1; o < 16; o <<= 1) {
        ss += __shfl_xor(ss, o);
        sd += __shfl_xor(sd, o);
      }
      if (row < M) {
        if (l16 == 0) {
          es[row * H + h] = ss * LOG2E;
          ed[row * H + h] = sd * LOG2E;
        }
        unsigned int pk = 0;
        pk = __builtin_amdgcn_cvt_pk_fp8_f32(acc[h * 4 + 0][r], acc[h * 4 + 1][r], pk, false);
        pk = __builtin_amdgcn_cvt_pk_fp8_f32(acc[h * 4 + 2][r], acc[h * 4 + 3][r], pk, true);
        *(unsigned int*)&C[(size_t)row * Nc + h * 64 + l16 * 4] = pk;
      }
    }
  }
}

// ------- aggregation, HC=256: fp8 gather, 4 edges/wave via quads, index-prefetch pipeline -------
__global__ void agg256_kernel(const unsigned char* __restrict__ h, const int* __restrict__ offsets,
                              const int* __restrict__ src_sorted, const float* __restrict__ es,
                              const float* __restrict__ ed, const float* __restrict__ bias,
                              __bf16* __restrict__ out, int n) {
  int node = blockIdx.x * (blockDim.x >> 6) + (threadIdx.x >> 6);
  int lane = threadIdx.x & 63;
  if (node >= n) return;
  int quad = lane >> 4;
  int l16 = lane & 15;  // positions l16*16 .. +16
  int hd = l16 >> 2;
  float myEd = ed[node * 4 + hd];
  int off = offsets[node];
  int deg = offsets[node + 1] - off;
  float acc[16] = {};
  float sw = 0.f;
  int j = 0;
  int s0a = 0, s1a = 0;
  if (j + 8 <= deg) {
    s0a = src_sorted[off + j + quad];
    s1a = src_sorted[off + j + 4 + quad];
  }
  for (; j + 8 <= deg;) {
    int jn = j + 8;
    int s0 = s0a, s1 = s1a;
    if (jn + 8 <= deg) {  // prefetch next iteration's indices
      s0a = src_sorted[off + jn + quad];
      s1a = src_sorted[off + jn + 4 + quad];
    }
    float e0 = es[s0 * 4 + hd];
    float e1 = es[s1 * 4 + hd];
    u32x4 u0 = *(const u32x4*)&h[(size_t)s0 * 256 + l16 * 16];
    u32x4 u1 = *(const u32x4*)&h[(size_t)s1 * 256 + l16 * 16];
    float w0 = fexp2(lrelu(e0 + myEd));
    float w1 = fexp2(lrelu(e1 + myEd));
    sw += w0 + w1;
    float f[16];
    dec16(u0, f);
#pragma unroll
    for (int k = 0; k < 16; k++) acc[k] += w0 * f[k];
    dec16(u1, f);
#pragma unroll
    for (int k = 0; k < 16; k++) acc[k] += w1 * f[k];
    j = jn;
  }
  for (; j < deg; j += 4) {  // tail: 1 edge per quad
    if (quad < deg - j) {
      int s = src_sorted[off + j + quad];
      float w = fexp2(lrelu(es[s * 4 + hd] + myEd));
      sw += w;
      u32x4 u = *(const u32x4*)&h[(size_t)s * 256 + l16 * 16];
      float f[16];
      dec16(u, f);
#pragma unroll
      for (int k = 0; k < 16; k++) acc[k] += w * f[k];
    }
  }
  sw += __shfl_xor(sw, 16);
  sw += __shfl_xor(sw, 32);
#pragma unroll
  for (int k = 0; k < 16; k++) {
    acc[k] += __shfl_xor(acc[k], 16);
    acc[k] += __shfl_xor(acc[k], 32);
  }
  float invS = 1.0f / (sw + 1e-16f);
  if (quad == 0) {
    bf16x8 o0, o1;
#pragma unroll
    for (int k = 0; k < 16; k++) {
      int c = hd * 64 + (k & 3) * 16 + (l16 & 3) * 4 + (k >> 2);  // cmap(l16*16+k)
      float v = fmaxf(acc[k] * invS + bias[c], 0.f);
      if (k < 8) o0[k] = (__bf16)v; else o1[k - 8] = (__bf16)v;
    }
    *(bf16x8*)&out[(size_t)node * 256 + l16 * 16] = o0;
    *(bf16x8*)&out[(size_t)node * 256 + l16 * 16 + 8] = o1;
  }
}

// ------- aggregation, HC=64 + FUSED final linear: p[i] = (agg_i + b2) . lin_w (fp8 gather) ------
__global__ void agg64_kernel(const unsigned char* __restrict__ h, const int* __restrict__ offsets,
                             const int* __restrict__ src_sorted, const float* __restrict__ es,
                             const float* __restrict__ ed, const float* __restrict__ bias,
                             const float* __restrict__ lin_w, float* __restrict__ pnode, int n) {
  int node = blockIdx.x * (blockDim.x >> 6) + (threadIdx.x >> 6);
  int lane = threadIdx.x & 63;
  if (node >= n) return;
  int grp = lane >> 3;
  int l8 = lane & 7;
  float myEd = ed[node];
  int off = offsets[node];
  int deg = offsets[node + 1] - off;
  float acc[8] = {};
  float sw = 0.f;
  int j = 0;
  for (; j + 8 <= deg; j += 8) {
    int s = src_sorted[off + j + grp];
    float w = fexp2(lrelu(es[s] + myEd));
    sw += w;
    u32x2 u = *(const u32x2*)&h[(size_t)s * 64 + l8 * 8];
    float f[8];
    dec8(u.x, u.y, f);
#pragma unroll
    for (int k = 0; k < 8; k++) acc[k] += w * f[k];
  }
  if (j < deg && grp < deg - j) {
    int s = src_sorted[off + j + grp];
    float w = fexp2(lrelu(es[s] + myEd));
    sw += w;
    u32x2 u = *(const u32x2*)&h[(size_t)s * 64 + l8 * 8];
    float f[8];
    dec8(u.x, u.y, f);
#pragma unroll
    for (int k = 0; k < 8; k++) acc[k] += w * f[k];
  }
#pragma unroll
  for (int o = 8; o < 64; o <<= 1) {
    sw += __shfl_xor(sw, o);
#pragma unroll
    for (int k = 0; k < 8; k++) acc[k] += __shfl_xor(acc[k], o);
  }
  float invS = 1.0f / (sw + 1e-16f);
  float p = 0.f;
#pragma unroll
  for (int k = 0; k < 8; k++) {
    int c = (k & 3) * 16 + l8 * 2 + (k >> 2);  // cmap(l8*8+k)
    p += (acc[k] * invS + bias[c]) * lin_w[c];
  }
#pragma unroll
  for (int o = 1; o < 8; o <<= 1) p += __shfl_xor(p, o);
  if (lane == 0) pnode[node] = p;
}

// ---------------- FUSED pool+final: block g binary-searches its segment, reduces, writes out ----
static __device__ __forceinline__ int lowerb(const int* __restrict__ a, int n, int key) {
  int lo = 0, hi = n;
  while (lo < hi) {
    int mid = (lo + hi) >> 1;
    if (a[mid] < key) lo = mid + 1; else hi = mid;
  }
  return lo;
}

__global__ void poolfinal_kernel(const float* __restrict__ pnode, const int* __restrict__ batch,
                                 const float* __restrict__ lin_b, float* __restrict__ out, int n) {
  __shared__ float ws[4];
  int g = blockIdx.x;
  int start = lowerb(batch, n, g);
  int end = lowerb(batch, n, g + 1);
  float acc = 0.f;
  for (int i = start + threadIdx.x; i < end; i += 256) acc += pnode[i];
  for (int o = 32; o > 0; o >>= 1) acc += __shfl_down(acc, o);
  if ((threadIdx.x & 63) == 0) ws[threadIdx.x >> 6] = acc;
  __syncthreads();
  if (threadIdx.x == 0) {
    float total = ws[0] + ws[1] + ws[2] + ws[3];
    out[g] = total / fmaxf((float)(end - start), 1.0f) + lin_b[0];
  }
}

extern "C" void kernel_launch(void* const* d_in, const int* in_sizes, int n_in, void* d_out,
                              int out_size, void* d_ws, size_t ws_size, hipStream_t stream) {
  const float* x = (const float*)d_in[0];
  const int* edge_index = (const int*)d_in[1];
  const int* batch = (const int*)d_in[2];
  const float* W0 = (const float*)d_in[3];
  const float* a_src0 = (const float*)d_in[4];
  const float* a_dst0 = (const float*)d_in[5];
  const float* b0 = (const float*)d_in[6];
  const float* W1 = (const float*)d_in[7];
  const float* a_src1 = (const float*)d_in[8];
  const float* a_dst1 = (const float*)d_in[9];
  const float* b1 = (const float*)d_in[10];
  const float* W2 = (const float*)d_in[11];
  const float* a_src2 = (const float*)d_in[12];
  const float* a_dst2 = (const float*)d_in[13];
  const float* b2 = (const float*)d_in[14];
  const float* lin_w = (const float*)d_in[15];
  const float* lin_b = (const float*)d_in[16];
  float* out = (float*)d_out;

  const int N = in_sizes[2];      // 50000
  const int E = in_sizes[1] / 2;  // 800000
  const int EE = E + N;
  const int G = 64;
  const int FIN = in_sizes[0] / N;  // 128

  const int* srcArr = edge_index;
  const int* dstArr = edge_index + E;

  // workspace carve (256B aligned)
  size_t off = 0;
  auto alloc = [&](size_t bytes) -> void* {
    off = (off + 255) & ~(size_t)255;
    void* p = (char*)d_ws + off;
    off += bytes;
    return p;
  };
  __bf16* xb = (__bf16*)alloc((size_t)N * FIN * 2);
  unsigned char* hA = (unsigned char*)alloc((size_t)N * 256);  // GEMM out, fp8 permuted
  __bf16* hB = (__bf16*)alloc((size_t)N * 256 * 2);            // aggregate out, bf16 permuted
  unsigned char* h2 = (unsigned char*)alloc((size_t)N * 64);   // layer2 GEMM out, fp8 permuted
  float* pnode = (float*)alloc((size_t)N * 4);
  __bf16* Bt0 = (__bf16*)alloc((size_t)256 * FIN * 2);
  __bf16* Bt1 = (__bf16*)alloc((size_t)256 * 256 * 2);
  __bf16* Bt2 = (__bf16*)alloc((size_t)64 * 256 * 2);
  float* es = (float*)alloc((size_t)N * 4 * 4);
  float* ed = (float*)alloc((size_t)N * 4 * 4);
  int* offsets = (int*)alloc((size_t)(N + 1) * 4);
  int* partials = (int*)alloc((size_t)64 * 4);
  int* rank = (int*)alloc((size_t)EE * 4);
  int* src_sorted = (int*)alloc((size_t)EE * 4);
  int* cnt = (int*)alloc((size_t)N * 4);
  (void)ws_size;

  int n4 = N * FIN / 4;
  int cb = (n4 + 255) / 256;
  int nz = (N + 255) / 256;
  int ebc4 = (EE + 1023) / 1024;  // 4 edges per thread (count/scatter)
  int nb = (N + 1023) / 1024;     // scan blocks
  int nwb = (N + 3) / 4;          // aggregate: one node per wave, 4 waves/block
  int gmx = (N + 63) / 64;        // GEMM M-blocks (64 rows each)

  // ---- prep (x->bf16, weight transposes, zero cnt) ----
  prep_kernel<<<cb + 576 + nz, 256, 0, stream>>>(x, xb, n4, W0, Bt0, W1, Bt1, W2, Bt2, FIN, cnt,
                                                 N);

  // ---- layer-0 GEMM + CSR count (fused; count's atomic cadence hides behind MFMA) ----
  count_gemm_kernel<128, 4><<<gmx + ebc4, 256, 0, stream>>>(
      xb, Bt0, a_src0, a_dst0, hA, es, ed, N, gmx, dstArr, cnt, rank, E, N);

  // ---- CSR scan + scatter (separate dispatches; r14's soft-barrier fusion regressed 8x) ----
  scan1_kernel<<<nb, 1024, 0, stream>>>(cnt, offsets, partials, N);
  scan3_kernel<<<nb, 1024, 0, stream>>>(offsets, partials, N, nb);
  scatter_kernel<<<ebc4, 256, 0, stream>>>(srcArr, dstArr, offsets, rank, src_sorted, E, N);

  // ---- layer 0 aggregate ----
  agg256_kernel<<<nwb, 256, 0, stream>>>(hA, offsets, src_sorted, es, ed, b0, hB, N);

  // ---- layer 1: 256 -> 4x64 concat, relu ----
  gemm2_kernel<256, 4><<<gmx, 256, 0, stream>>>(hB, Bt1, a_src1, a_dst1, hA, es, ed, N);
  agg256_kernel<<<nwb, 256, 0, stream>>>(hA, offsets, src_sorted, es, ed, b1, hB, N);

  // ---- layer 2: 256 -> 1x64, single head; final linear fused into aggregate ----
  gemm2_kernel<256, 1><<<gmx, 256, 0, stream>>>(hB, Bt2, a_src2, a_dst2, h2, es, ed, N);
  agg64_kernel<<<nwb, 256, 0, stream>>>(h2, offsets, src_sorted, es, ed, b2, lin_w, pnode, N);

  // ---- fused global mean pool + bias (binary-search segments) ----
  poolfinal_kernel<<<G, 256, 0, stream>>>(pnode, batch, lin_b, out, N);
}